// Round 1
// 529.052 us; speedup vs baseline: 1.0454x; 1.0454x over previous
//
#include <hip/hip_runtime.h>
#include <stdint.h>
#include <stddef.h>

typedef __bf16 bf16;
typedef __bf16 bf16x8 __attribute__((ext_vector_type(8)));
typedef float  f32x4  __attribute__((ext_vector_type(4)));

#define GLOBAL_AS(p) ((const __attribute__((address_space(1))) void*)(p))
#define LDS_AS(p)    ((__attribute__((address_space(3))) void*)(p))

__device__ __forceinline__ void gload_lds16(const bf16* g, bf16* l) {
    // global_load_lds_dwordx4: LDS dest = wave-uniform base + lane*16 (caller guarantees)
    __builtin_amdgcn_global_load_lds(GLOBAL_AS(g), LDS_AS(l), 16, 0, 0);
}

// ---------------------------------------------------------------------------
// x (f32) -> bf16, 8 elems/thread, both directions coalesced
// ---------------------------------------------------------------------------
__global__ __launch_bounds__(256)
void convert_x_kernel(const float* __restrict__ x, bf16* __restrict__ xb, long n8) {
    long t = (long)blockIdx.x * blockDim.x + threadIdx.x;
    if (t >= n8) return;
    const f32x4* p = (const f32x4*)(x + t * 8);
    f32x4 a = p[0], b = p[1];
    bf16x8 v;
#pragma unroll
    for (int j = 0; j < 4; ++j) { v[j] = (bf16)a[j]; v[4 + j] = (bf16)b[j]; }
    *(bf16x8*)(xb + t * 8) = v;
}

// ---------------------------------------------------------------------------
// Dequant to K-TILED layout for BK=64: Wt[K/64][N][64], Wt[t][o][cc] = W^T[o][t*64+cc]
//   = s[g][o]*(nib - z[g][o]),  nib = (qw[k/8, o] >> 4*(k%8)) & 15, g = k/G.
// Wave mapping: lane l -> rr = l&7 (qweight row in 8-row group), oo = l>>3.
//   stores: 64 lanes cover 8 o-rows x 128B  = 1KB contiguous per wave
// ---------------------------------------------------------------------------
__global__ __launch_bounds__(256)
void dequant_wt64_kernel(const uint32_t* __restrict__ qw,
                         const float* __restrict__ scales,
                         const float* __restrict__ qzeros,
                         bf16* __restrict__ Wt,
                         int N, int K, int rows_per_group) {
    const int i = blockIdx.x * 256 + threadIdx.x;
    const int w = i >> 6, l = i & 63;
    const int nr8 = K >> 6;                  // 8-row groups (64 k each)
    const int r8 = w % nr8;
    const int o  = (w / nr8) * 8 + (l >> 3);
    const int rr = l & 7;
    const int r  = r8 * 8 + rr;              // qweight row; k = r*8 + j
    if (o >= N) return;
    const uint32_t q = qw[(size_t)r * N + o];
    const int g = r / rows_per_group;
    const float s = scales[(size_t)g * N + o];
    const float z = qzeros[(size_t)g * N + o];
    const float nsz = -s * z;
    bf16x8 v;
#pragma unroll
    for (int j = 0; j < 8; ++j)
        v[j] = (bf16)fmaf((float)((q >> (4 * j)) & 15u), s, nsz);
    *(bf16x8*)(Wt + ((size_t)r8 * N + o) * 64 + rr * 8) = v;
}

// ===========================================================================
// 256x256 8-phase GEMM (T1+T2+T3+T4+T5).
//   8 waves (2M x 4N), BK=64, LDS = 2 bufs x (A 32KB + B 32KB) = 128KB.
//   Per wave: 128x64 C = acc[8][4] f32x4.  16 MFMA per phase (4i x 4j x 1kk).
//
// Phase schedule per iteration (2 K-tiles: T0=2i in buf0, T0+1 in buf1):
//   ph1: read a(buf0,kk0)+b(buf0,kk0); stage T1.B0  -> buf1 ; mfma i0-3 kk0
//   ph2: read a(buf0,kk1)            ; stage T1.B1  -> buf1 ; mfma i4-7 kk0
//   ph3: read b(buf0,kk1)            ; stage T2.A0  -> buf0 ; mfma i0-3 kk1
//   ph4:                              stage T2.A1  -> buf0 ; mfma i4-7 kk1 ; vmcnt(4)
//   ph5-8: same with buf1, stages T2.B0, T2.B1, T3.A0, T3.A1 ; vmcnt(4) at ph8
// Race audit (stage of region R must issue after the phase whose lgkmcnt(0)
// drains R's last ds_read; every phase fully drains lgkm before its close):
//   T2.A0 @ph3: A0 reads ph1,ph2 -> drained end-ph2. OK   T2.A1 @ph4: same. OK
//   T2.B0 @ph5: B0 reads ph1,ph3 -> end-ph3. OK           T2.B1 @ph6: same. OK
//   T3.A0 @ph7: buf1 A reads ph5,ph6 -> end-ph6. OK       T3.A1 @ph8: same. OK
//   T1.B0 @ph1: buf1 B reads prev ph5,ph7 -> end-prev-ph7. OK
// vmcnt(4) at ph4 drains through T1.B1 => tile T0+1 complete before ph5 reads.
// vmcnt(4) at ph8 drains through T2.B1 => tile T0+2 complete before next ph1.
// Tail: dummy (clamped-source) stages keep per-wave vmcnt counts exact.
//
// LDS swizzle (both-sides, rule #21): tiles are [256][64] bf16 (8 x 16B chunks
// per 128B row). Physical chunk p in row r holds logical chunk p ^ ((r>>1)&7):
// gload source address pre-applies the involution (LDS dest stays linear, as
// global_load_lds requires); ds_read applies the same XOR. Quarter-wave reads
// land 2 lanes per bank-quad => conflict-free (was 8-way).
// ===========================================================================
constexpr int BM2 = 256, BN2 = 256, BK2 = 64;

#define PHASE_MID()                                      \
    __builtin_amdgcn_s_barrier();                        \
    asm volatile("s_waitcnt lgkmcnt(0)" ::: "memory");   \
    __builtin_amdgcn_sched_barrier(0);                   \
    __builtin_amdgcn_s_setprio(1)

#define PHASE_END()                                      \
    __builtin_amdgcn_s_setprio(0);                       \
    __builtin_amdgcn_sched_barrier(0);                   \
    __builtin_amdgcn_s_barrier();                        \
    __builtin_amdgcn_sched_barrier(0)

#define PHASE_END_VM4()                                  \
    __builtin_amdgcn_s_setprio(0);                       \
    __builtin_amdgcn_sched_barrier(0);                   \
    asm volatile("s_waitcnt vmcnt(4)" ::: "memory");     \
    __builtin_amdgcn_s_barrier();                        \
    __builtin_amdgcn_sched_barrier(0)

#define MFMA_HALF(A, B, IBASE)                                             \
    _Pragma("unroll")                                                      \
    for (int i_ = 0; i_ < 4; ++i_) {                                       \
        _Pragma("unroll")                                                  \
        for (int j_ = 0; j_ < 4; ++j_)                                     \
            acc[(IBASE) + i_][j_] = __builtin_amdgcn_mfma_f32_16x16x32_bf16( \
                (A)[(IBASE) + i_], (B)[j_], acc[(IBASE) + i_][j_], 0, 0, 0); \
    }

__global__ __launch_bounds__(512, 2)
void gemm8_kernel(const bf16* __restrict__ Ab,   // [M][K] bf16
                  const bf16* __restrict__ Bt,   // [K/64][N][64] bf16 (= W^T k-tiled)
                  const float* __restrict__ bias,
                  float* __restrict__ out,
                  int M, int N, int K, int nbx) {
    __shared__ __align__(16) bf16 As[2][BM2 * BK2];   // 2 x 32KB
    __shared__ __align__(16) bf16 Bs[2][BN2 * BK2];   // 2 x 32KB

    const int tid  = threadIdx.x;
    const int lane = tid & 63;
    const int wave = tid >> 6;
    const int wm = wave >> 2;        // 0..1
    const int wn = wave & 3;         // 0..3

    // T1: bijective XCD swizzle (m204), then column-fast mapping so the 32
    // concurrent blocks on one XCD share a single 2MB B-panel (fits 4MB L2).
    const int nwg = gridDim.x;
    int wg = blockIdx.x;
    {
        const int q = nwg >> 3, r = nwg & 7;
        const int xcd = wg & 7, off = wg >> 3;
        wg = (xcd < r ? xcd * (q + 1) : r * (q + 1) + (xcd - r) * q) + off;
    }
    const int nby = nwg / nbx;
    const int bx = wg / nby;
    const int by = wg % nby;
    const int m0 = by * BM2;
    const int n0 = bx * BN2;

    const int lrow = lane & 15;
    const int lhi  = lane >> 4;
    const int swz  = (lrow >> 1) & 7;

    const int NT = K >> 6;           // K-tiles
    const int NI = NT >> 1;          // iterations (2 tiles each); K%128==0 guaranteed

    auto stageA = [&](int tIdx, int half, int buf) {
#pragma unroll
        for (int it = 0; it < 2; ++it) {
            const int q  = tid + it * 512;          // chunk in half-tile [0,1024)
            const int rl = q >> 3;                  // row within half
            const int cl = (q & 7) ^ ((rl >> 1) & 7);  // inverse-swizzled source chunk
            gload_lds16(Ab + (size_t)(m0 + half * 128 + rl) * K + tIdx * 64 + cl * 8,
                        &As[buf][half * 8192 + q * 8]);   // linear LDS dest
        }
    };
    auto stageB = [&](int tIdx, int half, int buf) {
#pragma unroll
        for (int it = 0; it < 2; ++it) {
            const int q  = tid + it * 512;
            const int rl = q >> 3;
            const int cl = (q & 7) ^ ((rl >> 1) & 7);
            gload_lds16(Bt + ((size_t)tIdx * N + n0 + half * 128 + rl) * 64 + cl * 8,
                        &Bs[buf][half * 8192 + q * 8]);
        }
    };

    f32x4 acc[8][4];
#pragma unroll
    for (int i = 0; i < 8; ++i)
#pragma unroll
        for (int j = 0; j < 4; ++j) acc[i][j] = (f32x4){0.f, 0.f, 0.f, 0.f};

    // prologue: tile0 complete (buf0) + tile1 A-halves (buf1) in flight
    stageA(0, 0, 0); stageA(0, 1, 0); stageB(0, 0, 0); stageB(0, 1, 0);
    stageA(1, 0, 1); stageA(1, 1, 1);
    asm volatile("s_waitcnt vmcnt(4)" ::: "memory");   // tile0's 8 loads landed
    __builtin_amdgcn_s_barrier();
    __builtin_amdgcn_sched_barrier(0);

    bf16x8 a0[8], a1[8], b0[4], b1[4];

    for (int i2 = 0; i2 < NI; ++i2) {
        const int t0  = 2 * i2;
        const int tS2 = (t0 + 2 < NT) ? t0 + 2 : NT - 1;  // clamped dummy at tail
        const int tS3 = (t0 + 3 < NT) ? t0 + 3 : NT - 1;

        // ---- phase 1: buf0 kk0 reads; stage T1.B0; mfma i0-3 kk0
#pragma unroll
        for (int i = 0; i < 8; ++i)
            a0[i] = *(const bf16x8*)(&As[0][(wm * 128 + i * 16 + lrow) * 64 + ((lhi ^ swz) * 8)]);
#pragma unroll
        for (int j = 0; j < 4; ++j)
            b0[j] = *(const bf16x8*)(&Bs[0][(wn * 64 + j * 16 + lrow) * 64 + ((lhi ^ swz) * 8)]);
        stageB(t0 + 1, 0, 1);
        PHASE_MID();
        MFMA_HALF(a0, b0, 0);
        PHASE_END();

        // ---- phase 2: read a kk1; stage T1.B1; mfma i4-7 kk0
#pragma unroll
        for (int i = 0; i < 8; ++i)
            a1[i] = *(const bf16x8*)(&As[0][(wm * 128 + i * 16 + lrow) * 64 + (((lhi + 4) ^ swz) * 8)]);
        stageB(t0 + 1, 1, 1);
        PHASE_MID();
        MFMA_HALF(a0, b0, 4);
        PHASE_END();

        // ---- phase 3: read b kk1; stage T2.A0; mfma i0-3 kk1
#pragma unroll
        for (int j = 0; j < 4; ++j)
            b1[j] = *(const bf16x8*)(&Bs[0][(wn * 64 + j * 16 + lrow) * 64 + (((lhi + 4) ^ swz) * 8)]);
        stageA(tS2, 0, 0);
        PHASE_MID();
        MFMA_HALF(a1, b1, 0);
        PHASE_END();

        // ---- phase 4: stage T2.A1; mfma i4-7 kk1; counted vmcnt
        stageA(tS2, 1, 0);
        PHASE_MID();
        MFMA_HALF(a1, b1, 4);
        PHASE_END_VM4();               // tile t0+1 fully landed; T2.A0/A1 in flight

        // ---- phase 5: buf1 kk0 reads; stage T2.B0; mfma i0-3 kk0
#pragma unroll
        for (int i = 0; i < 8; ++i)
            a0[i] = *(const bf16x8*)(&As[1][(wm * 128 + i * 16 + lrow) * 64 + ((lhi ^ swz) * 8)]);
#pragma unroll
        for (int j = 0; j < 4; ++j)
            b0[j] = *(const bf16x8*)(&Bs[1][(wn * 64 + j * 16 + lrow) * 64 + ((lhi ^ swz) * 8)]);
        stageB(tS2, 0, 0);
        PHASE_MID();
        MFMA_HALF(a0, b0, 0);
        PHASE_END();

        // ---- phase 6: read a kk1; stage T2.B1; mfma i4-7 kk0
#pragma unroll
        for (int i = 0; i < 8; ++i)
            a1[i] = *(const bf16x8*)(&As[1][(wm * 128 + i * 16 + lrow) * 64 + (((lhi + 4) ^ swz) * 8)]);
        stageB(tS2, 1, 0);
        PHASE_MID();
        MFMA_HALF(a0, b0, 4);
        PHASE_END();

        // ---- phase 7: read b kk1; stage T3.A0; mfma i0-3 kk1
#pragma unroll
        for (int j = 0; j < 4; ++j)
            b1[j] = *(const bf16x8*)(&Bs[1][(wn * 64 + j * 16 + lrow) * 64 + (((lhi + 4) ^ swz) * 8)]);
        stageA(tS3, 0, 1);
        PHASE_MID();
        MFMA_HALF(a1, b1, 0);
        PHASE_END();

        // ---- phase 8: stage T3.A1; mfma i4-7 kk1; counted vmcnt
        stageA(tS3, 1, 1);
        PHASE_MID();
        MFMA_HALF(a1, b1, 4);
        PHASE_END_VM4();               // tile t0+2 fully landed; T3.A0/A1 in flight
    }

    asm volatile("s_waitcnt vmcnt(0)" ::: "memory");   // drain before LDS dealloc

    // epilogue: D layout col=lane&15 (n), row=(lane>>4)*4+reg (m); f32 out
#pragma unroll
    for (int j = 0; j < 4; ++j) {
        const int col = n0 + wn * 64 + j * 16 + lrow;
        const float bv = bias[col];
#pragma unroll
        for (int i = 0; i < 8; ++i) {
            const int rbase = m0 + wm * 128 + i * 16 + lhi * 4;
#pragma unroll
            for (int r = 0; r < 4; ++r)
                out[(size_t)(rbase + r) * N + col] = acc[i][j][r] + bv;
        }
    }
}

// ---------------------------------------------------------------------------
// FUSED fallback (small-ws only): f32 x + qweight dequant in-flight.
// 128x128 tile, BK=32, 4 waves (2x2), 4x4 of mfma_f32_16x16x32_bf16.
// ---------------------------------------------------------------------------
constexpr int BM = 128, BN = 128, BK = 32;

__global__ __launch_bounds__(256)
void gemm_fused_kernel(const float* __restrict__ Af,      // [M,K] f32
                       const uint32_t* __restrict__ qw,   // [K/8,N]
                       const float* __restrict__ scales,  // [K/G,N] f32
                       const float* __restrict__ qzeros,  // [K/G,N] f32
                       const float* __restrict__ bias,    // [N] f32
                       float* __restrict__ out,           // [M,N] f32
                       int M, int N, int K, int G) {
    __shared__ __align__(16) bf16 As2[BM * BK];
    __shared__ __align__(16) bf16 Bs2[BN * BK];

    const int tid  = threadIdx.x;
    const int lane = tid & 63;
    const int wave = tid >> 6;
    const int wmm = wave & 1;
    const int wnn = wave >> 1;
    const int m0 = blockIdx.y * BM;
    const int n0 = blockIdx.x * BN;

    const int lr = lane & 15;
    const int lk8 = (lane >> 4) * 8;

    f32x4 acc[4][4];
#pragma unroll
    for (int i = 0; i < 4; ++i)
#pragma unroll
        for (int j = 0; j < 4; ++j) acc[i][j] = (f32x4){0.f, 0.f, 0.f, 0.f};

    for (int kt = 0; kt < K; kt += BK) {
#pragma unroll
        for (int it = 0; it < 2; ++it) {
            const int c = tid + it * 256;
            const int row = c >> 2;
            const int kc  = (c & 3) * 8;
            const f32x4* p = (const f32x4*)(Af + (size_t)(m0 + row) * K + kt + kc);
            f32x4 a = p[0], b = p[1];
            bf16x8 v;
#pragma unroll
            for (int j = 0; j < 4; ++j) { v[j] = (bf16)a[j]; v[4 + j] = (bf16)b[j]; }
            *(bf16x8*)(As2 + row * BK + kc) = v;
        }
        const int g = kt / G;
#pragma unroll
        for (int it = 0; it < 2; ++it) {
            const int idx = tid + it * 256;
            const int rl = idx >> 7;
            const int nl = idx & 127;
            uint32_t q = qw[(size_t)(kt / 8 + rl) * N + n0 + nl];
            float s = scales[(size_t)g * N + n0 + nl];
            float z = qzeros[(size_t)g * N + n0 + nl];
            float nsz = -s * z;
            bf16x8 v;
#pragma unroll
            for (int j = 0; j < 8; ++j)
                v[j] = (bf16)fmaf((float)((q >> (4 * j)) & 15u), s, nsz);
            *(bf16x8*)(Bs2 + nl * BK + rl * 8) = v;
        }
        __syncthreads();

        bf16x8 a[4], b[4];
#pragma unroll
        for (int i = 0; i < 4; ++i)
            a[i] = *(const bf16x8*)(As2 + (wmm * 64 + i * 16 + lr) * BK + lk8);
#pragma unroll
        for (int j = 0; j < 4; ++j)
            b[j] = *(const bf16x8*)(Bs2 + (wnn * 64 + j * 16 + lr) * BK + lk8);

#pragma unroll
        for (int i = 0; i < 4; ++i)
#pragma unroll
            for (int j = 0; j < 4; ++j)
                acc[i][j] = __builtin_amdgcn_mfma_f32_16x16x32_bf16(
                    a[i], b[j], acc[i][j], 0, 0, 0);
        __syncthreads();
    }

#pragma unroll
    for (int j = 0; j < 4; ++j) {
        const int col = n0 + wnn * 64 + j * 16 + (lane & 15);
        const float bv = bias[col];
#pragma unroll
        for (int i = 0; i < 4; ++i) {
            const int rbase = m0 + wmm * 64 + i * 16 + (lane >> 4) * 4;
#pragma unroll
            for (int r = 0; r < 4; ++r)
                out[(size_t)(rbase + r) * N + col] = acc[i][j][r] + bv;
        }
    }
}

extern "C" void kernel_launch(void* const* d_in, const int* in_sizes, int n_in,
                              void* d_out, int out_size, void* d_ws, size_t ws_size,
                              hipStream_t stream) {
    // fp16 reference tensors are stored as FLOAT32 by the harness
    const float*    x      = (const float*)d_in[0];
    const uint32_t* qw     = (const uint32_t*)d_in[1];
    const float*    scales = (const float*)d_in[2];
    const float*    qzeros = (const float*)d_in[3];
    const float*    bias   = (const float*)d_in[4];
    float*          out    = (float*)d_out;

    const int N = in_sizes[4];                 // 4096
    const int K = (in_sizes[1] / N) * 8;       // 4096
    const int M = in_sizes[0] / K;             // 8192
    const int G = K / (in_sizes[2] / N);       // 64

    const size_t xb_bytes = (size_t)M * K * sizeof(bf16);   // 64 MB
    const size_t wt_bytes = (size_t)N * K * sizeof(bf16);   // 32 MB

    const bool shape_ok = (M % BM2 == 0) && (N % BN2 == 0) && (K % 128 == 0) &&
                          (G % 8 == 0);

    if (shape_ok && ws_size >= xb_bytes + wt_bytes) {
        bf16* Xb = (bf16*)d_ws;
        bf16* Wt = (bf16*)((char*)d_ws + xb_bytes);
        const long n8 = (long)M * K / 8;
        convert_x_kernel<<<(int)((n8 + 255) / 256), 256, 0, stream>>>(x, Xb, n8);
        // waves = (K/64) * (N/8); threads = waves*64
        const long dq_threads = ((long)K >> 6) * (N / 8) * 64;
        dequant_wt64_kernel<<<(int)((dq_threads + 255) / 256), 256, 0, stream>>>(
            qw, scales, qzeros, Wt, N, K, G / 8);
        const int nbx = N / BN2;
        const int nwg = nbx * (M / BM2);       // 512
        gemm8_kernel<<<nwg, 512, 0, stream>>>(Xb, Wt, bias, out, M, N, K, nbx);
    } else {
        dim3 grid(N / BN, M / BM);
        gemm_fused_kernel<<<grid, 256, 0, stream>>>(
            x, qw, scales, qzeros, bias, out, M, N, K, G);
    }
}